// Round 13
// baseline (158.335 us; speedup 1.0000x reference)
//
#include <hip/hip_runtime.h>
#include <hip/hip_bf16.h>
#include <math.h>

#define NN 2048      // nodes
#define NE 4096      // edges
#define D 128
#define NODE_K 1024
#define EDGE_K 2048
#define CAP 64       // per-node incident-edge list capacity (mean degree 4)

typedef const __hip_bfloat16* bfp;
typedef unsigned short u16;
typedef __attribute__((ext_vector_type(8))) short short8;     // 8 bf16 (4 VGPRs)
typedef __attribute__((ext_vector_type(4))) float floatx4;    // MFMA acc

#define MFMA16(a, b, c) __builtin_amdgcn_mfma_f32_16x16x32_bf16(a, b, c, 0, 0, 0)

__device__ __forceinline__ float b2f(__hip_bfloat16 x) { return __bfloat162float(x); }

// dual-path loads: f=1 -> fp32 input, f=0 -> bf16 input (bf16->fp32 is exact)
__device__ __forceinline__ float ldx(const void* p, size_t i, int f) {
  return f ? ((const float*)p)[i] : b2f(((bfp)p)[i]);
}
__device__ __forceinline__ float4 ldx4(const void* p, size_t i4, int f) {
  if (f) return ((const float4*)p)[i4];
  ushort4 u = ((const ushort4*)p)[i4];
  float4 r;
  r.x = __uint_as_float(((unsigned)u.x) << 16);
  r.y = __uint_as_float(((unsigned)u.y) << 16);
  r.z = __uint_as_float(((unsigned)u.z) << 16);
  r.w = __uint_as_float(((unsigned)u.w) << 16);
  return r;
}

// RNE fp32 -> (bf16 hi, bf16 lo): x ~= hi + lo, dropped part ~2^-17 |x|
__device__ __forceinline__ void split2(float x, u16& hi, u16& lo) {
  unsigned u = __float_as_uint(x);
  unsigned h = (u + 0x7FFFu + ((u >> 16) & 1u)) >> 16;
  hi = (u16)h;
  float r = x - __uint_as_float(h << 16);
  unsigned v = __float_as_uint(r);
  lo = (u16)((v + 0x7FFFu + ((v >> 16) & 1u)) >> 16);
}
__device__ __forceinline__ void build_frags(const float* v8, short8& fh, short8& fl) {
  #pragma unroll
  for (int i = 0; i < 8; ++i) {
    u16 h, l;
    split2(v8[i], h, l);
    fh[i] = (short)h; fl[i] = (short)l;
  }
}

// per-block dtype detect from first 1024 halves of node_features (2 KB, L2-hot)
__device__ __forceinline__ int detect_f(const u16* raw, int* s4) {
  int t = threadIdx.x;
  int weird = 0;
  for (int i = t; i < 1024; i += blockDim.x) {
    unsigned int bits = ((unsigned int)raw[i]) << 16;
    float x = __uint_as_float(bits);
    float ax = fabsf(x);
    if (!(ax <= 1e3f) || (x != 0.f && ax < 1e-12f)) weird++;  // nan/inf/huge/denorm
  }
  #pragma unroll
  for (int m = 32; m >= 1; m >>= 1) weird += __shfl_xor(weird, m);
  int nw = (int)blockDim.x >> 6;
  if ((t & 63) == 0) s4[t >> 6] = weird;
  __syncthreads();
  int tot = 0;
  for (int i = 0; i < nw; ++i) tot += s4[i];
  return (tot > 50) ? 1 : 0;  // 1 => inputs are fp32
}

struct K1Args {
  const void *nf, *ef, *wrn, *wre;
  const void* w[7];              // we, wn, wq, wk, wv, wo, w1 (each 128x128)
  float *ns, *es;
  int *deg, *flag;
  u16 *wtHi, *wtLo;              // [7][128 n][128 k] (transposed + split)
  u16 *feHi, *feLo;              // [NN*D | NE*D] row-major feature splits
};

// ---------- K1: scores (fp64) + deg zero + flag + vectorized splits ----------
#define SCORE_BLOCKS ((NN + NE) / 4)   // 1536
#define WPREP_BLOCKS 112               // 28672 ushort4-tasks / 256
#define FSPLIT_BLOCKS 192              // 196608 float4-tasks / (256*4)
__global__ __launch_bounds__(256) void scores_prep_kernel(K1Args a) {
  __shared__ int s4[4];
  int b = blockIdx.x, t = threadIdx.x;
  int f = detect_f((const u16*)a.nf, s4);
  if (b < SCORE_BLOCKS) {
    int wid = b * 4 + (t >> 6), lane = t & 63;
    const void* base; const void* w; float* out; size_t r0;
    if (wid < NN) { base = a.nf; r0 = (size_t)wid * D; w = a.wrn; out = a.ns + wid; }
    else { int r = wid - NN; base = a.ef; r0 = (size_t)r * D; w = a.wre; out = a.es + r; }
    double p = (double)ldx(base, r0 + lane, f) * (double)ldx(w, lane, f)
             + (double)ldx(base, r0 + lane + 64, f) * (double)ldx(w, lane + 64, f);
    #pragma unroll
    for (int m = 32; m >= 1; m >>= 1) p += __shfl_xor(p, m);
    if (lane == 0) *out = (float)p;
  } else if (b == SCORE_BLOCKS) {
    if (t == 0) a.flag[0] = f;
    for (int i = t; i < NN; i += 256) a.deg[i] = 0;
  } else if (b <= SCORE_BLOCKS + WPREP_BLOCKS) {
    // weight split+transpose, coalesced ushort4 stores: Wt[n][k0..k0+3]
    int tau = (b - SCORE_BLOCKS - 1) * 256 + t;  // 0..28671
    int w = tau >> 12, rem = tau & 4095;
    int n = rem >> 5, k0 = (rem & 31) * 4;
    ushort4 hi, lo;
    split2(ldx(a.w[w], (size_t)(k0 + 0) * 128 + n, f), hi.x, lo.x);
    split2(ldx(a.w[w], (size_t)(k0 + 1) * 128 + n, f), hi.y, lo.y);
    split2(ldx(a.w[w], (size_t)(k0 + 2) * 128 + n, f), hi.z, lo.z);
    split2(ldx(a.w[w], (size_t)(k0 + 3) * 128 + n, f), hi.w, lo.w);
    ((ushort4*)a.wtHi)[tau] = hi;
    ((ushort4*)a.wtLo)[tau] = lo;
  } else {
    // feature split: float4 in, 2x ushort4 out (NF then EF, row-major)
    int fb = b - SCORE_BLOCKS - 1 - WPREP_BLOCKS;  // 0..191
    #pragma unroll
    for (int i = 0; i < 4; ++i) {
      int g4 = fb * 1024 + i * 256 + t;            // 0..196607
      float4 x = (g4 < NN * D / 4) ? ldx4(a.nf, g4, f)
                                   : ldx4(a.ef, g4 - NN * D / 4, f);
      ushort4 hi, lo;
      split2(x.x, hi.x, lo.x);
      split2(x.y, hi.y, lo.y);
      split2(x.z, hi.z, lo.z);
      split2(x.w, hi.w, lo.w);
      ((ushort4*)a.feHi)[g4] = hi;
      ((ushort4*)a.feLo)[g4] = lo;
    }
  }
}

// ---------- K2: node rank + edge rank + incident lists (16 tasks per staging) ----
#define NMB (NN / 16)   // 128
#define EMB (NE / 16)   // 256
__global__ __launch_bounds__(256) void mask_lists_kernel(
    const float* __restrict__ ns, const float* __restrict__ es,
    const int* __restrict__ src, const int* __restrict__ dst,
    int* __restrict__ node_mask, int* __restrict__ edge_topk,
    int* __restrict__ deg, int* __restrict__ lists) {
  __shared__ float s[NE];
  int b = blockIdx.x, t = threadIdx.x;
  int wave = t >> 6, lane = t & 63;
  if (b < NMB) {  // exact top-k rank, stable ties (== lax.top_k)
    for (int i = t; i < NN; i += 256) s[i] = ns[i];
    __syncthreads();
    #pragma unroll
    for (int ti = 0; ti < 4; ++ti) {
      int i = b * 16 + wave * 4 + ti;
      float si = s[i];
      int rank = 0;
      for (int j = lane; j < NN; j += 64) {
        float sj = s[j];
        rank += (sj > si) || (sj == si && j < i);
      }
      #pragma unroll
      for (int m = 32; m >= 1; m >>= 1) rank += __shfl_xor(rank, m);
      if (lane == 0) node_mask[i] = (rank < NODE_K) ? 1 : 0;
    }
  } else if (b < NMB + EMB) {
    for (int i = t; i < NE; i += 256) s[i] = es[i];
    __syncthreads();
    #pragma unroll
    for (int ti = 0; ti < 4; ++ti) {
      int i = (b - NMB) * 16 + wave * 4 + ti;
      float si = s[i];
      int rank = 0;
      for (int j = lane; j < NE; j += 64) {
        float sj = s[j];
        rank += (sj > si) || (sj == si && j < i);
      }
      #pragma unroll
      for (int m = 32; m >= 1; m >>= 1) rank += __shfl_xor(rank, m);
      if (lane == 0) edge_topk[i] = (rank < EDGE_K) ? 1 : 0;
    }
  } else {
    int e = (b - NMB - EMB) * 256 + t;
    if (e < NE) {
      int sn = src[e], dn = dst[e];
      int p = atomicAdd(&deg[sn], 1);
      if (p >= 0 && p < CAP) lists[sn * CAP + p] = e;
      if (dn != sn) {
        p = atomicAdd(&deg[dn], 1);
        if (p >= 0 && p < CAP) lists[dn * CAP + p] = e;
      }
    }
  }
}

// ---------- K3: MFMA h -> q,k,v. ROWS=8, grid=NE/8=512 (2 blocks/CU) ----------
// Zero A-rows (m>=8) give zero C-rows for free -> no layout surgery for the
// half-tile. Dual acc chains (edge/node); A-frags prefetched, B inline (L2-hot).
__global__ __launch_bounds__(512) void h_qkv_mfma_kernel(
    const u16* __restrict__ feHi, const u16* __restrict__ feLo,
    const int* __restrict__ src, const int* __restrict__ dst,
    const int* __restrict__ node_mask, const int* __restrict__ edge_topk,
    const u16* __restrict__ wtHi, const u16* __restrict__ wtLo,
    float* __restrict__ qkv) {
  __shared__ __align__(16) float hf[8 * 64 * 4];  // frag-order h (fp32), 8 KB
  int t = threadIdx.x;
  int wave = t >> 6, lane = t & 63;
  int qd = lane >> 4, c = lane & 15;
  int row0 = blockIdx.x * 8;
  bool valid = c < 8;
  int e = row0 + (valid ? c : 0);
  int sn = src[e], dn = dst[e];
  bool em = valid && edge_topk[e] && node_mask[sn] && node_mask[dn];
  int n0 = wave * 16;
  const u16* efH = feHi + (size_t)NN * D;
  const u16* efL = feLo + (size_t)NN * D;
  const short8 z8 = {0, 0, 0, 0, 0, 0, 0, 0};

  // prefetch A-side frags (scattered gathers = the latency-critical loads)
  short8 A1h[4], A1l[4], Sh[4], Sl[4], Dh[4], Dl[4];
  #pragma unroll
  for (int ks = 0; ks < 4; ++ks) {
    int k0 = ks * 32 + qd * 8;
    A1h[ks] = *(const short8*)(efH + (size_t)e * D + k0);
    A1l[ks] = *(const short8*)(efL + (size_t)e * D + k0);
    Sh[ks]  = *(const short8*)(feHi + (size_t)sn * D + k0);
    Sl[ks]  = *(const short8*)(feLo + (size_t)sn * D + k0);
    Dh[ks]  = *(const short8*)(feHi + (size_t)dn * D + k0);
    Dl[ks]  = *(const short8*)(feLo + (size_t)dn * D + k0);
  }
  if (!em) {
    #pragma unroll
    for (int ks = 0; ks < 4; ++ks) { A1h[ks] = z8; A1l[ks] = z8; }
  }
  if (!valid) {
    #pragma unroll
    for (int ks = 0; ks < 4; ++ks) { Sh[ks] = z8; Sl[ks] = z8; Dh[ks] = z8; Dl[ks] = z8; }
  }
  floatx4 accE = {0.f, 0.f, 0.f, 0.f};
  floatx4 accN = {0.f, 0.f, 0.f, 0.f};
  #pragma unroll
  for (int ks = 0; ks < 4; ++ks) {
    size_t bo = (size_t)(n0 + c) * 128 + ks * 32 + qd * 8;
    short8 bEh = *(const short8*)(wtHi + bo);
    short8 bEl = *(const short8*)(wtLo + bo);
    short8 bNh = *(const short8*)(wtHi + 16384 + bo);
    short8 bNl = *(const short8*)(wtLo + 16384 + bo);
    accE = MFMA16(A1h[ks], bEh, accE);
    accN = MFMA16(Sh[ks], bNh, accN);
    accE = MFMA16(A1l[ks], bEh, accE);
    accN = MFMA16(Sl[ks], bNh, accN);
    accE = MFMA16(A1h[ks], bEl, accE);
    accN = MFMA16(Sh[ks], bNl, accN);
    accN = MFMA16(Dh[ks], bNh, accN);
    accN = MFMA16(Dl[ks], bNh, accN);
    accN = MFMA16(Dh[ks], bNl, accN);
  }
  // write h into frag-order LDS (rows 8-15 are naturally zero)
  {
    int np = n0 + c;
    int kd = np >> 5, qq = (np >> 3) & 3, half = (c >> 2) & 1, j4 = c & 3;
    #pragma unroll
    for (int r = 0; r < 4; ++r)
      hf[((kd * 2 + half) * 64 + qq * 16 + 4 * qd + r) * 4 + j4] = accE[r] + accN[r];
  }
  __syncthreads();
  // q,k,v: build h-frags ONCE per ks, feed 3 accumulator chains
  floatx4 aq = {0.f, 0.f, 0.f, 0.f};
  floatx4 ak = {0.f, 0.f, 0.f, 0.f};
  floatx4 av = {0.f, 0.f, 0.f, 0.f};
  #pragma unroll
  for (int ks = 0; ks < 4; ++ks) {
    float4 p0 = *(const float4*)&hf[((ks * 2 + 0) * 64 + lane) * 4];
    float4 p1 = *(const float4*)&hf[((ks * 2 + 1) * 64 + lane) * 4];
    float v8[8] = {p0.x, p0.y, p0.z, p0.w, p1.x, p1.y, p1.z, p1.w};
    short8 ah, al;
    build_frags(v8, ah, al);
    size_t bo = (size_t)(n0 + c) * 128 + ks * 32 + qd * 8;
    short8 BQh = *(const short8*)(wtHi + 2 * 16384 + bo);
    short8 BKh = *(const short8*)(wtHi + 3 * 16384 + bo);
    short8 BVh = *(const short8*)(wtHi + 4 * 16384 + bo);
    short8 BQl = *(const short8*)(wtLo + 2 * 16384 + bo);
    short8 BKl = *(const short8*)(wtLo + 3 * 16384 + bo);
    short8 BVl = *(const short8*)(wtLo + 4 * 16384 + bo);
    aq = MFMA16(ah, BQh, aq);
    ak = MFMA16(ah, BKh, ak);
    av = MFMA16(ah, BVh, av);
    aq = MFMA16(al, BQh, aq);
    ak = MFMA16(al, BKh, ak);
    av = MFMA16(al, BVh, av);
    aq = MFMA16(ah, BQl, aq);
    ak = MFMA16(ah, BKl, ak);
    av = MFMA16(ah, BVl, av);
  }
  if (qd < 2) {  // rows 4*qd+r in 0..7 are the real ones
    #pragma unroll
    for (int r = 0; r < 4; ++r) {
      size_t ro = (size_t)(row0 + 4 * qd + r) * D + n0 + c;
      qkv[ro] = aq[r];
      qkv[(size_t)NE * D + ro] = ak[r];
      qkv[(size_t)2 * NE * D + ro] = av[r];
    }
  }
}

// ---------- K4: sparse edge attention, one block (128 thr) per query edge --------
__global__ void attn_kernel(const float* __restrict__ q, const float* __restrict__ k,
                            const float* __restrict__ v, const int* __restrict__ src,
                            const int* __restrict__ dst, const int* __restrict__ deg,
                            const int* __restrict__ lists, float* __restrict__ ao) {
  int e = blockIdx.x;
  int j = threadIdx.x;  // head = j/32, d = j%32 (shfl_xor<32 stays in-head)
  float qj = q[(size_t)e * D + j];
  int sn = src[e], dn = dst[e];
  float m = -1e30f, l = 0.f, acc = 0.f;
  const float scale = 0.17677669529663687f;  // 1/sqrt(32)
  int degA = max(0, min(deg[sn], CAP));
  for (int i = 0; i < degA; ++i) {
    int fe = lists[sn * CAP + i];
    float p = qj * k[(size_t)fe * D + j];
    p += __shfl_xor(p, 16); p += __shfl_xor(p, 8); p += __shfl_xor(p, 4);
    p += __shfl_xor(p, 2);  p += __shfl_xor(p, 1);
    float s = p * scale;
    float vj = v[(size_t)fe * D + j];
    float mn = fmaxf(m, s);
    float corr = expf(m - mn);
    float w = expf(s - mn);
    l = l * corr + w;
    acc = acc * corr + w * vj;
    m = mn;
  }
  if (dn != sn) {
    int degB = max(0, min(deg[dn], CAP));
    for (int i = 0; i < degB; ++i) {
      int fe = lists[dn * CAP + i];
      if (src[fe] == sn || dst[fe] == sn) continue;  // already in list A
      float p = qj * k[(size_t)fe * D + j];
      p += __shfl_xor(p, 16); p += __shfl_xor(p, 8); p += __shfl_xor(p, 4);
      p += __shfl_xor(p, 2);  p += __shfl_xor(p, 1);
      float s = p * scale;
      float vj = v[(size_t)fe * D + j];
      float mn = fmaxf(m, s);
      float corr = expf(m - mn);
      float w = expf(s - mn);
      l = l * corr + w;
      acc = acc * corr + w * vj;
      m = mn;
    }
  }
  ao[(size_t)e * D + j] = acc / fmaxf(l, 1e-37f);
}

// ---------- K5: MFMA o -> gelu MLP -> logits. ROWS=8, grid=512 ----------
__global__ __launch_bounds__(512) void o_mlp_mfma_kernel(
    const float* __restrict__ ao,
    const u16* __restrict__ wtHi, const u16* __restrict__ wtLo,
    const void* __restrict__ b1, const void* __restrict__ w2,
    const void* __restrict__ b2, const int* __restrict__ flag,
    void* __restrict__ out) {
  __shared__ __align__(16) float hf[8 * 64 * 4];  // frag-order o (8 KB)
  __shared__ float xl[8 * 132];                   // x row-major, padded
  __shared__ float w2l[128 * 16];
  int t = threadIdx.x;
  int wave = t >> 6, lane = t & 63;
  int qd = lane >> 4, c = lane & 15;
  int f = flag[0];
  int row0 = blockIdx.x * 8;
  bool valid = c < 8;
  int n0 = wave * 16;
  const float zero8[8] = {0, 0, 0, 0, 0, 0, 0, 0};

  // o = ao @ WO (A gathered straight from global fp32; rows >=8 zero)
  floatx4 acc = {0.f, 0.f, 0.f, 0.f};
  #pragma unroll
  for (int ks = 0; ks < 4; ++ks) {
    int k0 = ks * 32 + qd * 8;
    float v8[8];
    if (valid) {
      const float* ap = ao + (size_t)(row0 + c) * D + k0;
      float4 p0 = *(const float4*)ap;
      float4 p1 = *(const float4*)(ap + 4);
      v8[0] = p0.x; v8[1] = p0.y; v8[2] = p0.z; v8[3] = p0.w;
      v8[4] = p1.x; v8[5] = p1.y; v8[6] = p1.z; v8[7] = p1.w;
    } else {
      #pragma unroll
      for (int i = 0; i < 8; ++i) v8[i] = zero8[i];
    }
    short8 ah, al;
    build_frags(v8, ah, al);
    size_t bo = (size_t)(n0 + c) * 128 + k0;
    short8 bh = *(const short8*)(wtHi + 5 * 16384 + bo);
    short8 bl = *(const short8*)(wtLo + 5 * 16384 + bo);
    acc = MFMA16(ah, bh, acc);
    acc = MFMA16(al, bh, acc);
    acc = MFMA16(ah, bl, acc);
  }
  {
    int np = n0 + c;
    int kd = np >> 5, qq = (np >> 3) & 3, half = (c >> 2) & 1, j4 = c & 3;
    #pragma unroll
    for (int r = 0; r < 4; ++r)
      hf[((kd * 2 + half) * 64 + qq * 16 + 4 * qd + r) * 4 + j4] = acc[r];
  }
  __syncthreads();
  // x = gelu(o @ W1 + b1)
  floatx4 a2c = {0.f, 0.f, 0.f, 0.f};
  #pragma unroll
  for (int ks = 0; ks < 4; ++ks) {
    float4 p0 = *(const float4*)&hf[((ks * 2 + 0) * 64 + lane) * 4];
    float4 p1 = *(const float4*)&hf[((ks * 2 + 1) * 64 + lane) * 4];
    float v8[8] = {p0.x, p0.y, p0.z, p0.w, p1.x, p1.y, p1.z, p1.w};
    short8 ah, al;
    build_frags(v8, ah, al);
    size_t bo = (size_t)(n0 + c) * 128 + ks * 32 + qd * 8;
    short8 bh = *(const short8*)(wtHi + 6 * 16384 + bo);
    short8 bl = *(const short8*)(wtLo + 6 * 16384 + bo);
    a2c = MFMA16(ah, bh, a2c);
    a2c = MFMA16(al, bh, a2c);
    a2c = MFMA16(ah, bl, a2c);
  }
  float bj = ldx(b1, n0 + c, f);
  if (qd < 2) {  // rows 0..7 only
    #pragma unroll
    for (int r = 0; r < 4; ++r) {
      float u = a2c[r] + bj;
      float inner = 0.7978845608028654f * (u + 0.044715f * u * u * u);
      xl[(4 * qd + r) * 132 + n0 + c] = 0.5f * u * (1.f + tanhf(inner));
    }
  }
  for (int i = t; i < D * 16; i += 512) w2l[i] = ldx(w2, i, f);
  __syncthreads();
  if (t < 128) {  // logits = x @ w2 + b2 (8 rows x 16 classes)
    int r = t >> 4, cc = t & 15;
    float s = 0.f;
    for (int kk = 0; kk < D; ++kk) s += xl[r * 132 + kk] * w2l[kk * 16 + cc];
    s += ldx(b2, cc, f);
    int idx = (row0 + r) * 16 + cc;
    if (f) ((float*)out)[idx] = s;
    else ((__hip_bfloat16*)out)[idx] = __float2bfloat16(s);
  }
}

extern "C" void kernel_launch(void* const* d_in, const int* in_sizes, int n_in,
                              void* d_out, int out_size, void* d_ws, size_t ws_size,
                              hipStream_t stream) {
  const int* eidx = (const int*)d_in[2];
  const int* src = eidx;
  const int* dst = eidx + NE;

  size_t off = 0;
  char* base = (char*)d_ws;
  auto alloc = [&](size_t nbytes) -> void* {
    void* p = base + off;
    off += (nbytes + 255) & ~(size_t)255;
    return p;
  };
  int* flag      = (int*)alloc(256);
  float* ns      = (float*)alloc(NN * sizeof(float));
  float* es      = (float*)alloc(NE * sizeof(float));
  int* node_mask = (int*)alloc(NN * sizeof(int));
  int* edge_topk = (int*)alloc(NE * sizeof(int));
  int* deg       = (int*)alloc(NN * sizeof(int));
  int* lists     = (int*)alloc((size_t)NN * CAP * sizeof(int));
  u16* wtHi      = (u16*)alloc((size_t)7 * 16384 * sizeof(u16));
  u16* wtLo      = (u16*)alloc((size_t)7 * 16384 * sizeof(u16));
  u16* feHi      = (u16*)alloc((size_t)(NN + NE) * D * sizeof(u16));
  u16* feLo      = (u16*)alloc((size_t)(NN + NE) * D * sizeof(u16));
  float* qkv     = (float*)alloc((size_t)3 * NE * D * sizeof(float));
  float* ao      = (float*)alloc((size_t)NE * D * sizeof(float));
  float* qb = qkv, *kb = qkv + NE * D, *vb = qkv + 2 * NE * D;

  K1Args a1;
  a1.nf = d_in[0]; a1.ef = d_in[1]; a1.wrn = d_in[3]; a1.wre = d_in[4];
  a1.w[0] = d_in[5];  a1.w[1] = d_in[6];  a1.w[2] = d_in[7];
  a1.w[3] = d_in[8];  a1.w[4] = d_in[9];  a1.w[5] = d_in[10]; a1.w[6] = d_in[11];
  a1.ns = ns; a1.es = es; a1.deg = deg; a1.flag = flag;
  a1.wtHi = wtHi; a1.wtLo = wtLo; a1.feHi = feHi; a1.feLo = feLo;

  // K1: scores + flag + deg zero + vectorized weight/feature splits
  scores_prep_kernel<<<SCORE_BLOCKS + 1 + WPREP_BLOCKS + FSPLIT_BLOCKS, 256, 0,
                       stream>>>(a1);
  // K2: top-k ranks + incident lists (16 tasks per staged block)
  mask_lists_kernel<<<NMB + EMB + NE / 256, 256, 0, stream>>>(
      ns, es, src, dst, node_mask, edge_topk, deg, lists);
  // K3: MFMA h -> q,k,v (8 rows/block, 512 blocks = 2/CU)
  h_qkv_mfma_kernel<<<NE / 8, 512, 0, stream>>>(
      feHi, feLo, src, dst, node_mask, edge_topk, wtHi, wtLo, qkv);
  // K4: sparse attention
  attn_kernel<<<NE, 128, 0, stream>>>(qb, kb, vb, src, dst, deg, lists, ao);
  // K5: MFMA o -> gelu MLP -> logits (8 rows/block, 512 blocks)
  o_mlp_mfma_kernel<<<NE / 8, 512, 0, stream>>>(
      ao, wtHi, wtLo, d_in[12], d_in[13], d_in[14], flag, d_out);
}

// Round 14
// 136.513 us; speedup vs baseline: 1.1598x; 1.1598x over previous
//
#include <hip/hip_runtime.h>
#include <hip/hip_bf16.h>
#include <math.h>

#define NN 2048      // nodes
#define NE 4096      // edges
#define D 128
#define NODE_K 1024
#define EDGE_K 2048
#define CAP 64       // per-node incident-edge list capacity (mean degree 4)

typedef const __hip_bfloat16* bfp;
typedef unsigned short u16;
typedef __attribute__((ext_vector_type(8))) short short8;     // 8 bf16 (4 VGPRs)
typedef __attribute__((ext_vector_type(4))) float floatx4;    // MFMA acc

#define MFMA16(a, b, c) __builtin_amdgcn_mfma_f32_16x16x32_bf16(a, b, c, 0, 0, 0)

__device__ __forceinline__ float b2f(__hip_bfloat16 x) { return __bfloat162float(x); }

// dual-path loads: f=1 -> fp32 input, f=0 -> bf16 input (bf16->fp32 is exact)
__device__ __forceinline__ float ldx(const void* p, size_t i, int f) {
  return f ? ((const float*)p)[i] : b2f(((bfp)p)[i]);
}
__device__ __forceinline__ float4 ldx4(const void* p, size_t i4, int f) {
  if (f) return ((const float4*)p)[i4];
  ushort4 u = ((const ushort4*)p)[i4];
  float4 r;
  r.x = __uint_as_float(((unsigned)u.x) << 16);
  r.y = __uint_as_float(((unsigned)u.y) << 16);
  r.z = __uint_as_float(((unsigned)u.z) << 16);
  r.w = __uint_as_float(((unsigned)u.w) << 16);
  return r;
}

// RNE fp32 -> (bf16 hi, bf16 lo): x ~= hi + lo, dropped part ~2^-17 |x|
__device__ __forceinline__ void split2(float x, u16& hi, u16& lo) {
  unsigned u = __float_as_uint(x);
  unsigned h = (u + 0x7FFFu + ((u >> 16) & 1u)) >> 16;
  hi = (u16)h;
  float r = x - __uint_as_float(h << 16);
  unsigned v = __float_as_uint(r);
  lo = (u16)((v + 0x7FFFu + ((v >> 16) & 1u)) >> 16);
}
__device__ __forceinline__ void build_frags(const float* v8, short8& fh, short8& fl) {
  #pragma unroll
  for (int i = 0; i < 8; ++i) {
    u16 h, l;
    split2(v8[i], h, l);
    fh[i] = (short)h; fl[i] = (short)l;
  }
}

// per-block dtype detect from first 1024 halves of node_features (2 KB, L2-hot)
__device__ __forceinline__ int detect_f(const u16* raw, int* s4) {
  int t = threadIdx.x;
  int weird = 0;
  for (int i = t; i < 1024; i += blockDim.x) {
    unsigned int bits = ((unsigned int)raw[i]) << 16;
    float x = __uint_as_float(bits);
    float ax = fabsf(x);
    if (!(ax <= 1e3f) || (x != 0.f && ax < 1e-12f)) weird++;  // nan/inf/huge/denorm
  }
  #pragma unroll
  for (int m = 32; m >= 1; m >>= 1) weird += __shfl_xor(weird, m);
  int nw = (int)blockDim.x >> 6;
  if ((t & 63) == 0) s4[t >> 6] = weird;
  __syncthreads();
  int tot = 0;
  for (int i = 0; i < nw; ++i) tot += s4[i];
  return (tot > 50) ? 1 : 0;  // 1 => inputs are fp32
}

struct K1Args {
  const void *nf, *ef, *wrn, *wre;
  const void* w[7];              // we, wn, wq, wk, wv, wo, w1 (each 128x128)
  float *ns, *es;
  int *deg, *flag;
  u16 *wtHi, *wtLo;              // [7][128 n][128 k] (transposed + split)
  u16 *feHi, *feLo;              // [NN*D | NE*D] row-major feature splits
};

// ---------- K1: scores (fp64) + deg zero + flag + vectorized splits ----------
#define SCORE_BLOCKS ((NN + NE) / 4)   // 1536
#define WPREP_BLOCKS 112               // 28672 ushort4-tasks / 256
#define FSPLIT_BLOCKS 192              // 196608 float4-tasks / (256*4)
__global__ __launch_bounds__(256) void scores_prep_kernel(K1Args a) {
  __shared__ int s4[4];
  int b = blockIdx.x, t = threadIdx.x;
  int f = detect_f((const u16*)a.nf, s4);
  if (b < SCORE_BLOCKS) {
    int wid = b * 4 + (t >> 6), lane = t & 63;
    const void* base; const void* w; float* out; size_t r0;
    if (wid < NN) { base = a.nf; r0 = (size_t)wid * D; w = a.wrn; out = a.ns + wid; }
    else { int r = wid - NN; base = a.ef; r0 = (size_t)r * D; w = a.wre; out = a.es + r; }
    double p = (double)ldx(base, r0 + lane, f) * (double)ldx(w, lane, f)
             + (double)ldx(base, r0 + lane + 64, f) * (double)ldx(w, lane + 64, f);
    #pragma unroll
    for (int m = 32; m >= 1; m >>= 1) p += __shfl_xor(p, m);
    if (lane == 0) *out = (float)p;
  } else if (b == SCORE_BLOCKS) {
    if (t == 0) a.flag[0] = f;
    for (int i = t; i < NN; i += 256) a.deg[i] = 0;
  } else if (b <= SCORE_BLOCKS + WPREP_BLOCKS) {
    // weight split+transpose, coalesced ushort4 stores: Wt[n][k0..k0+3]
    int tau = (b - SCORE_BLOCKS - 1) * 256 + t;  // 0..28671
    int w = tau >> 12, rem = tau & 4095;
    int n = rem >> 5, k0 = (rem & 31) * 4;
    ushort4 hi, lo;
    split2(ldx(a.w[w], (size_t)(k0 + 0) * 128 + n, f), hi.x, lo.x);
    split2(ldx(a.w[w], (size_t)(k0 + 1) * 128 + n, f), hi.y, lo.y);
    split2(ldx(a.w[w], (size_t)(k0 + 2) * 128 + n, f), hi.z, lo.z);
    split2(ldx(a.w[w], (size_t)(k0 + 3) * 128 + n, f), hi.w, lo.w);
    ((ushort4*)a.wtHi)[tau] = hi;
    ((ushort4*)a.wtLo)[tau] = lo;
  } else {
    // feature split: float4 in, 2x ushort4 out (NF then EF, row-major)
    int fb = b - SCORE_BLOCKS - 1 - WPREP_BLOCKS;  // 0..191
    #pragma unroll
    for (int i = 0; i < 4; ++i) {
      int g4 = fb * 1024 + i * 256 + t;            // 0..196607
      float4 x = (g4 < NN * D / 4) ? ldx4(a.nf, g4, f)
                                   : ldx4(a.ef, g4 - NN * D / 4, f);
      ushort4 hi, lo;
      split2(x.x, hi.x, lo.x);
      split2(x.y, hi.y, lo.y);
      split2(x.z, hi.z, lo.z);
      split2(x.w, hi.w, lo.w);
      ((ushort4*)a.feHi)[g4] = hi;
      ((ushort4*)a.feLo)[g4] = lo;
    }
  }
}

// ---------- K2: node rank + edge rank + incident lists ----------
#define NMB (NN / 4)
#define EMB (NE / 4)
__global__ __launch_bounds__(256) void mask_lists_kernel(
    const float* __restrict__ ns, const float* __restrict__ es,
    const int* __restrict__ src, const int* __restrict__ dst,
    int* __restrict__ node_mask, int* __restrict__ edge_topk,
    int* __restrict__ deg, int* __restrict__ lists) {
  __shared__ __align__(16) float s[NE];
  int b = blockIdx.x, t = threadIdx.x;
  if (b < NMB) {  // exact top-k rank, stable ties (== lax.top_k)
    for (int i = t; i < NN / 4; i += 256) ((float4*)s)[i] = ((const float4*)ns)[i];
    __syncthreads();
    int i = b * 4 + (t >> 6), lane = t & 63;
    float si = s[i];
    int rank = 0;
    for (int j = lane; j < NN; j += 64) {
      float sj = s[j];
      rank += (sj > si) || (sj == si && j < i);
    }
    #pragma unroll
    for (int m = 32; m >= 1; m >>= 1) rank += __shfl_xor(rank, m);
    if (lane == 0) node_mask[i] = (rank < NODE_K) ? 1 : 0;
  } else if (b < NMB + EMB) {
    for (int i = t; i < NE / 4; i += 256) ((float4*)s)[i] = ((const float4*)es)[i];
    __syncthreads();
    int i = (b - NMB) * 4 + (t >> 6), lane = t & 63;
    float si = s[i];
    int rank = 0;
    for (int j = lane; j < NE; j += 64) {
      float sj = s[j];
      rank += (sj > si) || (sj == si && j < i);
    }
    #pragma unroll
    for (int m = 32; m >= 1; m >>= 1) rank += __shfl_xor(rank, m);
    if (lane == 0) edge_topk[i] = (rank < EDGE_K) ? 1 : 0;
  } else {
    int e = (b - NMB - EMB) * 256 + t;
    if (e < NE) {
      int sn = src[e], dn = dst[e];
      int p = atomicAdd(&deg[sn], 1);
      if (p >= 0 && p < CAP) lists[sn * CAP + p] = e;
      if (dn != sn) {
        p = atomicAdd(&deg[dn], 1);
        if (p >= 0 && p < CAP) lists[dn * CAP + p] = e;
      }
    }
  }
}

// ---------- K3: MFMA h = efm@WE + (nfs+nfd)@WN; q,k,v = h@WQ/WK/WV ----------
// 512 thr (8 waves), 16 edge rows/block; wave w owns col-tile n0 = w*16.
// A-frags prefetched (latency-critical gathers), B inline (L2-hot);
// dual acc chains (edge/node) double MFMA ILP.
__global__ __launch_bounds__(512) void h_qkv_mfma_kernel(
    const u16* __restrict__ feHi, const u16* __restrict__ feLo,
    const int* __restrict__ src, const int* __restrict__ dst,
    const int* __restrict__ node_mask, const int* __restrict__ edge_topk,
    const u16* __restrict__ wtHi, const u16* __restrict__ wtLo,
    float* __restrict__ qkv) {
  __shared__ __align__(16) float hf[8 * 64 * 4];  // frag-order h (fp32), 8 KB
  int t = threadIdx.x;
  int wave = t >> 6, lane = t & 63;
  int qd = lane >> 4, c = lane & 15;
  int row0 = blockIdx.x * 16;
  int e = row0 + c;                 // A-row this lane gathers (m = c)
  int sn = src[e], dn = dst[e];
  bool em = edge_topk[e] && node_mask[sn] && node_mask[dn];
  int n0 = wave * 16;
  const u16* efH = feHi + (size_t)NN * D;
  const u16* efL = feLo + (size_t)NN * D;
  const short8 z8 = {0, 0, 0, 0, 0, 0, 0, 0};

  // prefetch ALL h-pass A-operands (24 x 16B independent loads in flight)
  short8 A1h[4], A1l[4], Sh[4], Sl[4], Dh[4], Dl[4];
  short8 BEh[4], BEl[4], BNh[4], BNl[4];
  #pragma unroll
  for (int ks = 0; ks < 4; ++ks) {
    int k0 = ks * 32 + qd * 8;
    A1h[ks] = *(const short8*)(efH + (size_t)e * D + k0);
    A1l[ks] = *(const short8*)(efL + (size_t)e * D + k0);
    Sh[ks]  = *(const short8*)(feHi + (size_t)sn * D + k0);
    Sl[ks]  = *(const short8*)(feLo + (size_t)sn * D + k0);
    Dh[ks]  = *(const short8*)(feHi + (size_t)dn * D + k0);
    Dl[ks]  = *(const short8*)(feLo + (size_t)dn * D + k0);
    size_t bo = (size_t)(n0 + c) * 128 + k0;
    BEh[ks] = *(const short8*)(wtHi + bo);
    BEl[ks] = *(const short8*)(wtLo + bo);
    BNh[ks] = *(const short8*)(wtHi + 16384 + bo);
    BNl[ks] = *(const short8*)(wtLo + 16384 + bo);
  }
  if (!em) {
    #pragma unroll
    for (int ks = 0; ks < 4; ++ks) { A1h[ks] = z8; A1l[ks] = z8; }
  }
  floatx4 accE = {0.f, 0.f, 0.f, 0.f};
  floatx4 accN = {0.f, 0.f, 0.f, 0.f};
  #pragma unroll
  for (int ks = 0; ks < 4; ++ks) {
    accE = MFMA16(A1h[ks], BEh[ks], accE);
    accN = MFMA16(Sh[ks], BNh[ks], accN);
    accE = MFMA16(A1l[ks], BEh[ks], accE);
    accN = MFMA16(Sl[ks], BNh[ks], accN);
    accE = MFMA16(A1h[ks], BEl[ks], accE);
    accN = MFMA16(Sh[ks], BNl[ks], accN);
    accN = MFMA16(Dh[ks], BNh[ks], accN);
    accN = MFMA16(Dl[ks], BNh[ks], accN);
    accN = MFMA16(Dh[ks], BNl[ks], accN);
  }
  // write h (C-layout: row=4*qd+r, col=n0+c) into frag-order LDS
  {
    int np = n0 + c;
    int kd = np >> 5, qq = (np >> 3) & 3, half = (c >> 2) & 1, j4 = c & 3;
    #pragma unroll
    for (int r = 0; r < 4; ++r)
      hf[((kd * 2 + half) * 64 + qq * 16 + 4 * qd + r) * 4 + j4] = accE[r] + accN[r];
  }
  // prefetch q/k/v B-frags while h settles
  short8 BQh[4], BQl[4], BKh[4], BKl[4], BVh[4], BVl[4];
  #pragma unroll
  for (int ks = 0; ks < 4; ++ks) {
    size_t bo = (size_t)(n0 + c) * 128 + ks * 32 + qd * 8;
    BQh[ks] = *(const short8*)(wtHi + 2 * 16384 + bo);
    BQl[ks] = *(const short8*)(wtLo + 2 * 16384 + bo);
    BKh[ks] = *(const short8*)(wtHi + 3 * 16384 + bo);
    BKl[ks] = *(const short8*)(wtLo + 3 * 16384 + bo);
    BVh[ks] = *(const short8*)(wtHi + 4 * 16384 + bo);
    BVl[ks] = *(const short8*)(wtLo + 4 * 16384 + bo);
  }
  __syncthreads();
  // q,k,v: build h-frags ONCE per ks, feed 3 accumulator chains
  floatx4 aq = {0.f, 0.f, 0.f, 0.f};
  floatx4 ak = {0.f, 0.f, 0.f, 0.f};
  floatx4 av = {0.f, 0.f, 0.f, 0.f};
  #pragma unroll
  for (int ks = 0; ks < 4; ++ks) {
    float4 p0 = *(const float4*)&hf[((ks * 2 + 0) * 64 + lane) * 4];
    float4 p1 = *(const float4*)&hf[((ks * 2 + 1) * 64 + lane) * 4];
    float v8[8] = {p0.x, p0.y, p0.z, p0.w, p1.x, p1.y, p1.z, p1.w};
    short8 ah, al;
    build_frags(v8, ah, al);
    aq = MFMA16(ah, BQh[ks], aq);
    ak = MFMA16(ah, BKh[ks], ak);
    av = MFMA16(ah, BVh[ks], av);
    aq = MFMA16(al, BQh[ks], aq);
    ak = MFMA16(al, BKh[ks], ak);
    av = MFMA16(al, BVh[ks], av);
    aq = MFMA16(ah, BQl[ks], aq);
    ak = MFMA16(ah, BKl[ks], ak);
    av = MFMA16(ah, BVl[ks], av);
  }
  #pragma unroll
  for (int r = 0; r < 4; ++r) {
    size_t ro = (size_t)(row0 + 4 * qd + r) * D + n0 + c;
    qkv[ro] = aq[r];
    qkv[(size_t)NE * D + ro] = ak[r];
    qkv[(size_t)2 * NE * D + ro] = av[r];
  }
}

// ---------- K4: sparse edge attention, one block (128 thr) per query edge --------
__global__ void attn_kernel(const float* __restrict__ q, const float* __restrict__ k,
                            const float* __restrict__ v, const int* __restrict__ src,
                            const int* __restrict__ dst, const int* __restrict__ deg,
                            const int* __restrict__ lists, float* __restrict__ ao) {
  int e = blockIdx.x;
  int j = threadIdx.x;  // head = j/32, d = j%32 (shfl_xor<32 stays in-head)
  float qj = q[(size_t)e * D + j];
  int sn = src[e], dn = dst[e];
  float m = -1e30f, l = 0.f, acc = 0.f;
  const float scale = 0.17677669529663687f;  // 1/sqrt(32)
  int degA = max(0, min(deg[sn], CAP));
  for (int i = 0; i < degA; ++i) {
    int fe = lists[sn * CAP + i];
    float p = qj * k[(size_t)fe * D + j];
    p += __shfl_xor(p, 16); p += __shfl_xor(p, 8); p += __shfl_xor(p, 4);
    p += __shfl_xor(p, 2);  p += __shfl_xor(p, 1);
    float s = p * scale;
    float vj = v[(size_t)fe * D + j];
    float mn = fmaxf(m, s);
    float corr = expf(m - mn);
    float w = expf(s - mn);
    l = l * corr + w;
    acc = acc * corr + w * vj;
    m = mn;
  }
  if (dn != sn) {
    int degB = max(0, min(deg[dn], CAP));
    for (int i = 0; i < degB; ++i) {
      int fe = lists[dn * CAP + i];
      if (src[fe] == sn || dst[fe] == sn) continue;  // already in list A
      float p = qj * k[(size_t)fe * D + j];
      p += __shfl_xor(p, 16); p += __shfl_xor(p, 8); p += __shfl_xor(p, 4);
      p += __shfl_xor(p, 2);  p += __shfl_xor(p, 1);
      float s = p * scale;
      float vj = v[(size_t)fe * D + j];
      float mn = fmaxf(m, s);
      float corr = expf(m - mn);
      float w = expf(s - mn);
      l = l * corr + w;
      acc = acc * corr + w * vj;
      m = mn;
    }
  }
  ao[(size_t)e * D + j] = acc / fmaxf(l, 1e-37f);
}

// ---------- K5: MFMA o = ao@WO; x = gelu(o@W1+b1); logits = x@W2+b2 ----------
__global__ __launch_bounds__(512) void o_mlp_mfma_kernel(
    const float* __restrict__ ao,
    const u16* __restrict__ wtHi, const u16* __restrict__ wtLo,
    const void* __restrict__ b1, const void* __restrict__ w2,
    const void* __restrict__ b2, const int* __restrict__ flag,
    void* __restrict__ out) {
  __shared__ __align__(16) float hf[8 * 64 * 4];  // frag-order o (8 KB)
  __shared__ float xl[16 * 132];                  // x row-major, padded
  __shared__ float w2l[128 * 16];
  int t = threadIdx.x;
  int wave = t >> 6, lane = t & 63;
  int qd = lane >> 4, c = lane & 15;
  int f = flag[0];
  int row0 = blockIdx.x * 16;
  int n0 = wave * 16;

  // prefetch both passes' B-frags
  short8 BOh[4], BOl[4], B1h[4], B1l[4];
  #pragma unroll
  for (int ks = 0; ks < 4; ++ks) {
    size_t bo = (size_t)(n0 + c) * 128 + ks * 32 + qd * 8;
    BOh[ks] = *(const short8*)(wtHi + 5 * 16384 + bo);
    BOl[ks] = *(const short8*)(wtLo + 5 * 16384 + bo);
    B1h[ks] = *(const short8*)(wtHi + 6 * 16384 + bo);
    B1l[ks] = *(const short8*)(wtLo + 6 * 16384 + bo);
  }
  // o = ao @ WO (A gathered straight from global fp32)
  floatx4 acc = {0.f, 0.f, 0.f, 0.f};
  #pragma unroll
  for (int ks = 0; ks < 4; ++ks) {
    int k0 = ks * 32 + qd * 8;
    const float* ap = ao + (size_t)(row0 + c) * D + k0;
    float4 p0 = *(const float4*)ap;
    float4 p1 = *(const float4*)(ap + 4);
    float v8[8] = {p0.x, p0.y, p0.z, p0.w, p1.x, p1.y, p1.z, p1.w};
    short8 ah, al;
    build_frags(v8, ah, al);
    acc = MFMA16(ah, BOh[ks], acc);
    acc = MFMA16(al, BOh[ks], acc);
    acc = MFMA16(ah, BOl[ks], acc);
  }
  {
    int np = n0 + c;
    int kd = np >> 5, qq = (np >> 3) & 3, half = (c >> 2) & 1, j4 = c & 3;
    #pragma unroll
    for (int r = 0; r < 4; ++r)
      hf[((kd * 2 + half) * 64 + qq * 16 + 4 * qd + r) * 4 + j4] = acc[r];
  }
  __syncthreads();
  // x = gelu(o @ W1 + b1)
  floatx4 a2c = {0.f, 0.f, 0.f, 0.f};
  #pragma unroll
  for (int ks = 0; ks < 4; ++ks) {
    float4 p0 = *(const float4*)&hf[((ks * 2 + 0) * 64 + lane) * 4];
    float4 p1 = *(const float4*)&hf[((ks * 2 + 1) * 64 + lane) * 4];
    float v8[8] = {p0.x, p0.y, p0.z, p0.w, p1.x, p1.y, p1.z, p1.w};
    short8 ah, al;
    build_frags(v8, ah, al);
    a2c = MFMA16(ah, B1h[ks], a2c);
    a2c = MFMA16(al, B1h[ks], a2c);
    a2c = MFMA16(ah, B1l[ks], a2c);
  }
  float bj = ldx(b1, n0 + c, f);
  #pragma unroll
  for (int r = 0; r < 4; ++r) {
    float u = a2c[r] + bj;
    float inner = 0.7978845608028654f * (u + 0.044715f * u * u * u);
    xl[(4 * qd + r) * 132 + n0 + c] = 0.5f * u * (1.f + tanhf(inner));
  }
  for (int i = t; i < D * 16; i += 512) w2l[i] = ldx(w2, i, f);
  __syncthreads();
  if (t < 256) {  // logits = x @ w2 + b2
    int r = t >> 4, cc = t & 15;
    float s = 0.f;
    for (int kk = 0; kk < D; ++kk) s += xl[r * 132 + kk] * w2l[kk * 16 + cc];
    s += ldx(b2, cc, f);
    int idx = (row0 + r) * 16 + cc;
    if (f) ((float*)out)[idx] = s;
    else ((__hip_bfloat16*)out)[idx] = __float2bfloat16(s);
  }
}

extern "C" void kernel_launch(void* const* d_in, const int* in_sizes, int n_in,
                              void* d_out, int out_size, void* d_ws, size_t ws_size,
                              hipStream_t stream) {
  const int* eidx = (const int*)d_in[2];
  const int* src = eidx;
  const int* dst = eidx + NE;

  size_t off = 0;
  char* base = (char*)d_ws;
  auto alloc = [&](size_t nbytes) -> void* {
    void* p = base + off;
    off += (nbytes + 255) & ~(size_t)255;
    return p;
  };
  int* flag      = (int*)alloc(256);
  float* ns      = (float*)alloc(NN * sizeof(float));
  float* es      = (float*)alloc(NE * sizeof(float));
  int* node_mask = (int*)alloc(NN * sizeof(int));
  int* edge_topk = (int*)alloc(NE * sizeof(int));
  int* deg       = (int*)alloc(NN * sizeof(int));
  int* lists     = (int*)alloc((size_t)NN * CAP * sizeof(int));
  u16* wtHi      = (u16*)alloc((size_t)7 * 16384 * sizeof(u16));
  u16* wtLo      = (u16*)alloc((size_t)7 * 16384 * sizeof(u16));
  u16* feHi      = (u16*)alloc((size_t)(NN + NE) * D * sizeof(u16));
  u16* feLo      = (u16*)alloc((size_t)(NN + NE) * D * sizeof(u16));
  float* qkv     = (float*)alloc((size_t)3 * NE * D * sizeof(float));
  float* ao      = (float*)alloc((size_t)NE * D * sizeof(float));
  float* qb = qkv, *kb = qkv + NE * D, *vb = qkv + 2 * NE * D;

  K1Args a1;
  a1.nf = d_in[0]; a1.ef = d_in[1]; a1.wrn = d_in[3]; a1.wre = d_in[4];
  a1.w[0] = d_in[5];  a1.w[1] = d_in[6];  a1.w[2] = d_in[7];
  a1.w[3] = d_in[8];  a1.w[4] = d_in[9];  a1.w[5] = d_in[10]; a1.w[6] = d_in[11];
  a1.ns = ns; a1.es = es; a1.deg = deg; a1.flag = flag;
  a1.wtHi = wtHi; a1.wtLo = wtLo; a1.feHi = feHi; a1.feLo = feLo;

  // K1: scores + flag + deg zero + vectorized weight/feature splits
  scores_prep_kernel<<<SCORE_BLOCKS + 1 + WPREP_BLOCKS + FSPLIT_BLOCKS, 256, 0,
                       stream>>>(a1);
  // K2: top-k ranks + incident lists
  mask_lists_kernel<<<NMB + EMB + NE / 256, 256, 0, stream>>>(
      ns, es, src, dst, node_mask, edge_topk, deg, lists);
  // K3: MFMA h -> q,k,v
  h_qkv_mfma_kernel<<<NE / 16, 512, 0, stream>>>(
      feHi, feLo, src, dst, node_mask, edge_topk, wtHi, wtLo, qkv);
  // K4: sparse attention
  attn_kernel<<<NE, 128, 0, stream>>>(qb, kb, vb, src, dst, deg, lists, ao);
  // K5: MFMA o -> gelu MLP -> logits
  o_mlp_mfma_kernel<<<NE / 16, 512, 0, stream>>>(
      ao, wtHi, wtLo, d_in[12], d_in[13], d_in[14], flag, d_out);
}